// Round 5
// baseline (415.390 us; speedup 1.0000x reference)
//
#include <hip/hip_runtime.h>
#include <cstdint>
#include <cmath>

// y_pred [B,D,1] f32, y_true [B,D,1] f32, pO_slot [K] f32, gumbel [S,B,D] f32
constexpr int KS   = 10;        // K_SLOTS
constexpr int DD   = 120;       // D
constexpr int BB   = 4096;      // B
constexpr int SS   = 128;       // S
constexpr int ROWS = SS * BB;   // 524288 rows; row r = s*B + b (contiguous in b)
constexpr int TPB  = 256;
constexpr int NBLK = ROWS / TPB;   // 2048 (4096%256==0 -> block never straddles s)
constexpr int PH   = 8;            // phases per block
constexpr int PC   = DD / PH;      // 15 floats per row per phase (odd -> LDS conflict-free)
constexpr int PHW  = TPB * PC;     // 3840 dwords per phase slab

// async global->LDS, dword granularity; LDS dest is linear (wave base + lane*4)
#define GLDS(gp, lp) __builtin_amdgcn_global_load_lds(                     \
    (const __attribute__((address_space(1))) void*)(gp),                   \
    (__attribute__((address_space(3))) void*)(lp), 4, 0, 0)

// One thread = one (s,b) row; 8 phases of 15 cols. Gumbel AND y_pred slabs
// staged coalesced via global_load_lds (4 lines/wave-load vs 64 scattered in
// r1/r4 -> fixes the MSHR/latency wall at 1.25 TB/s). Double-buffered, 60 KB
// LDS -> 2 blocks/CU. Per-row math identical to the round-1 passing kernel.
__global__ __launch_bounds__(TPB, 2) void vlpl_topk(
    const float* __restrict__ y_pred,
    const float* __restrict__ y_true,
    const float* __restrict__ pO,
    const float* __restrict__ gumbel,
    float* __restrict__ partials)
{
    __shared__ float gbuf[2][PHW];   // gumbel phase slabs
    __shared__ float pbuf[2][PHW];   // y_pred phase slabs
    __shared__ float wsum[TPB / 64];

    const int t   = threadIdx.x;
    const int blk = blockIdx.x;
    // gumbel slab for this block: rows blk*256 .. +255 (contiguous, 30720 dwords)
    const float* __restrict__ gslab = gumbel + (size_t)blk * (TPB * DD);
    // y_pred slab: b-range (blk&15)*256 .. +255
    const float* __restrict__ pslab = y_pred + (size_t)(blk & (BB / TPB - 1)) * (TPB * DD);

    // phase-0 dword offsets for this thread's 15 coalesced loads:
    //   j = i*256 + t ; row = j/15 ; col = j%15 ; off = row*120 + col
    // (phase p adds p*15). Hoisted once -> 15 regs, reused by all 8 phases.
    int offd[PC];
#pragma unroll
    for (int i = 0; i < PC; ++i) {
        const int j   = i * TPB + t;
        const int row = j / PC;
        offd[i] = row * DD + (j - row * PC);
    }

    // prologue: stage phase 0 into buffer 0
#pragma unroll
    for (int i = 0; i < PC; ++i) {
        const int j = i * TPB + t;
        GLDS(gslab + offd[i], &gbuf[0][j]);
        GLDS(pslab + offd[i], &pbuf[0][j]);
    }
    __syncthreads();   // drains vmcnt + barrier

    float val[KS];
#pragma unroll
    for (int k = 0; k < KS; ++k) val[k] = -INFINITY;

#pragma unroll
    for (int p = 0; p < PH; ++p) {
        const int cur = p & 1;          // compile-time (full unroll)
        if (p + 1 < PH) {               // issue next phase's stage first (latency hides under compute)
#pragma unroll
            for (int i = 0; i < PC; ++i) {
                const int j   = i * TPB + t;
                const int off = offd[i] + (p + 1) * PC;
                GLDS(gslab + off, &gbuf[cur ^ 1][j]);
                GLDS(pslab + off, &pbuf[cur ^ 1][j]);
            }
        }
        // compute current phase from LDS: row stride 15 dwords (odd) -> no bank conflicts
        const float* __restrict__ gr = &gbuf[cur][t * PC];
        const float* __restrict__ pr = &pbuf[cur][t * PC];
#pragma unroll
        for (int c = 0; c < PC; ++c) {
            const float e = gr[c] + pr[c];
            const uint32_t j = (uint32_t)(p * PC + c);   // doc index, compile-time literal
            // embed 7-bit index in low mantissa (order kept except ties < 2^-16 rel)
            float v = __uint_as_float((__float_as_uint(e) & 0xFFFFFF80u) | j);
#pragma unroll
            for (int k = 0; k < KS; ++k) {               // branch-free sorted-desc insert
                const float hi = fmaxf(val[k], v);
                v      = fminf(val[k], v);
                val[k] = hi;
            }
        }
        __syncthreads();   // next-phase stage complete + buffer safe to flip
    }

    // slot-weighted reward; yt gather is tiny (10 hits/row, L2-hot)
    const int b = (blk & (BB / TPB - 1)) * TPB + t;
    const float* __restrict__ yt = y_true + (size_t)b * DD;
    float reward = 0.f;
#pragma unroll
    for (int k = 0; k < KS; ++k) {
        const uint32_t idx = __float_as_uint(val[k]) & 127u;
        reward = fmaf(pO[k], yt[idx], reward);
    }

    // block reduction: wave64 shuffle -> LDS across 4 waves -> one partial/block
#pragma unroll
    for (int off = 32; off >= 1; off >>= 1)
        reward += __shfl_down(reward, off, 64);
    const int lane = t & 63;
    const int wid  = t >> 6;
    if (lane == 0) wsum[wid] = reward;
    __syncthreads();
    if (t == 0) {
        float s = 0.f;
#pragma unroll
        for (int w = 0; w < TPB / 64; ++w) s += wsum[w];
        partials[blk] = s;
    }
}

__global__ __launch_bounds__(256) void vlpl_reduce(
    const float* __restrict__ partials, float* __restrict__ out)
{
    double acc = 0.0;
    for (int i = threadIdx.x; i < NBLK; i += 256) acc += (double)partials[i];
#pragma unroll
    for (int off = 32; off >= 1; off >>= 1)
        acc += __shfl_down(acc, off, 64);
    __shared__ double dsum[4];
    const int lane = threadIdx.x & 63;
    const int wid  = threadIdx.x >> 6;
    if (lane == 0) dsum[wid] = acc;
    __syncthreads();
    if (threadIdx.x == 0) {
        const double s = dsum[0] + dsum[1] + dsum[2] + dsum[3];
        out[0] = (float)(s * (1.0 / (double)ROWS));
    }
}

extern "C" void kernel_launch(void* const* d_in, const int* in_sizes, int n_in,
                              void* d_out, int out_size, void* d_ws, size_t ws_size,
                              hipStream_t stream)
{
    const float* y_pred = (const float*)d_in[0];
    const float* y_true = (const float*)d_in[1];
    const float* pO     = (const float*)d_in[2];
    const float* gumbel = (const float*)d_in[3];

    float* partials = (float*)d_ws;   // 2048 floats, overwritten every call
    float* out      = (float*)d_out;

    vlpl_topk<<<NBLK, TPB, 0, stream>>>(y_pred, y_true, pO, gumbel, partials);
    vlpl_reduce<<<1, 256, 0, stream>>>(partials, out);
}